// Round 2
// baseline (277.725 us; speedup 1.0000x reference)
//
#include <hip/hip_runtime.h>
#include <math.h>

#define L_SEQ 32768
#define NBLK 128   // blocks in chain kernel

// ---------------------------------------------------------------------------
// Device-scope barrier for the persistent chain kernel. cnt starts at 0
// (hipMemsetAsync before launch); target = NBLK * barrier_index (monotonic,
// never reset during the kernel -> no reuse hazard).
// ---------------------------------------------------------------------------
__device__ __forceinline__ void gbar(int* cnt, int target) {
  __syncthreads();
  if (threadIdx.x == 0) {
    __hip_atomic_fetch_add(cnt, 1, __ATOMIC_RELEASE, __HIP_MEMORY_SCOPE_AGENT);
    while (__hip_atomic_load(cnt, __ATOMIC_ACQUIRE, __HIP_MEMORY_SCOPE_AGENT) < target) {
      __builtin_amdgcn_s_sleep(2);
    }
  }
  __syncthreads();
}

__device__ __forceinline__ float dot128(const float* __restrict__ Ar,
                                        const float* __restrict__ B,
                                        int ldb, int j) {
  float a0 = 0.f, a1 = 0.f, a2 = 0.f, a3 = 0.f;
#pragma unroll
  for (int k = 0; k < 128; k += 4) {
    a0 = fmaf(Ar[k],     B[(k)     * ldb + j], a0);
    a1 = fmaf(Ar[k + 1], B[(k + 1) * ldb + j], a1);
    a2 = fmaf(Ar[k + 2], B[(k + 2) * ldb + j], a2);
    a3 = fmaf(Ar[k + 3], B[(k + 3) * ldb + j], a3);
  }
  return (a0 + a1) + (a2 + a3);
}

// ---------------------------------------------------------------------------
// Persistent kernel: entire matrix chain (Neumann inverse -> ab -> power
// doubling for R (128x256) and S (128x128) -> K = S*R) in ONE launch.
// 128 blocks x 256 threads = 32768 threads; each step does up to 2 matmul
// jobs (tid<16384 / tid>=16384), separated by device barriers.
// ---------------------------------------------------------------------------
__global__ __launch_bounds__(256) void chain_k(const float* __restrict__ A,
                                               const float* __restrict__ Bv,
                                               const float* __restrict__ Cv,
                                               const float* __restrict__ lstep,
                                               float* ws) {
  int* cnt   = (int*)ws;
  float* T   = ws + 16;
  float* U1  = T   + 16384;
  float* T2  = U1  + 16384;
  float* T4  = T2  + 16384;
  float* T8  = T4  + 16384;
  float* U12 = T8  + 16384;
  float* U48 = U12 + 16384;
  float* ab  = U48 + 16384;   // = pw(0)
  float* pwA = ab  + 16384;
  float* pwB = pwA + 16384;
  float* R   = pwB + 16384;   // 128 x 256 row-major
  float* S   = R   + 32768;   // 128 x 128 row-major
  float* Kv  = S   + 16384;   // 32768

  int tid = blockIdx.x * 256 + threadIdx.x;
  float step = expf(lstep[0]);
  int bar = 0;

  // s0: T = alpha*(A+2I), U1 = I + T,  alpha = (step/2)/(1+step)
  if (tid < 16384) {
    int i = tid >> 7, j = tid & 127;
    float alpha = 0.5f * step / (1.0f + step);
    float g = A[tid] + ((i == j) ? 2.0f : 0.0f);
    float t = alpha * g;
    T[tid] = t;
    U1[tid] = t + ((i == j) ? 1.0f : 0.0f);
  }
  gbar(cnt, NBLK * (++bar));

  // s1: T2 = T*T
  if (tid < 16384) {
    int i = tid >> 7, j = tid & 127;
    T2[tid] = dot128(T + i * 128, T, 128, j);
  }
  gbar(cnt, NBLK * (++bar));

  // s2: T4 = T2*T2  |  U12 = U1*T2 + U1
  if (tid < 16384) {
    int i = tid >> 7, j = tid & 127;
    T4[tid] = dot128(T2 + i * 128, T2, 128, j);
  } else {
    int t2 = tid - 16384;
    int i = t2 >> 7, j = t2 & 127;
    U12[t2] = dot128(U1 + i * 128, T2, 128, j) + U1[t2];
  }
  gbar(cnt, NBLK * (++bar));

  // s3: T8 = T4*T4
  if (tid < 16384) {
    int i = tid >> 7, j = tid & 127;
    T8[tid] = dot128(T4 + i * 128, T4, 128, j);
  }
  gbar(cnt, NBLK * (++bar));

  // s4: U48 = T4*T8 + T4 + T8 + I
  if (tid < 16384) {
    int i = tid >> 7, j = tid & 127;
    U48[tid] = dot128(T4 + i * 128, T8, 128, j) + T4[tid] + T8[tid] +
               ((i == j) ? 1.f : 0.f);
  }
  gbar(cnt, NBLK * (++bar));

  // s5: ab = (2/(1+step)) * U12*U48 - I
  if (tid < 16384) {
    int i = tid >> 7, j = tid & 127;
    ab[tid] = (2.f / (1.f + step)) * dot128(U12 + i * 128, U48, 128, j) -
              ((i == j) ? 1.f : 0.f);
  }
  gbar(cnt, NBLK * (++bar));

  // s6: prep  bb = (step/2)*(ab*B + B) -> R col 0 ;  S row 0 = C
  if (tid < 128) {
    float acc = 0.f;
    for (int k = 0; k < 128; ++k) acc = fmaf(ab[tid * 128 + k], Bv[k], acc);
    R[tid * 256] = 0.5f * step * (acc + Bv[tid]);
  } else if (tid < 256) {
    S[tid - 128] = Cv[tid - 128];
  }
  gbar(cnt, NBLK * (++bar));

  // R doubling: R[:, 2^k + j] = pw(k) * R[:, j]  |  pw(k+1) = pw(k)^2
  for (int k = 0; k < 8; ++k) {
    const float* pwk = (k == 0) ? ab : ((k & 1) ? pwA : pwB);
    float* pwn = ((k + 1) & 1) ? pwA : pwB;
    if (tid < (128 << k)) {
      int i = tid >> k, j = tid & ((1 << k) - 1);
      R[i * 256 + (1 << k) + j] = dot128(pwk + i * 128, R, 256, j);
    } else if (tid >= 16384) {
      int t2 = tid - 16384;
      int i = t2 >> 7, j = t2 & 127;
      pwn[t2] = dot128(pwk + i * 128, pwk, 128, j);
    }
    gbar(cnt, NBLK * (++bar));
  }

  // S doubling: S[2^k + i, :] = S[i, :] * pw(8+k)  |  pw(9+k) = pw(8+k)^2
  for (int k = 0; k < 7; ++k) {
    const float* pwk = ((8 + k) & 1) ? pwA : pwB;
    float* pwn = ((9 + k) & 1) ? pwA : pwB;
    if (tid < (128 << k)) {
      int i = tid >> 7, j = tid & 127;
      S[((1 << k) + i) * 128 + j] = dot128(S + i * 128, pwk, 128, j);
    } else if (k < 6 && tid >= 16384) {
      int t2 = tid - 16384;
      int i = t2 >> 7, j = t2 & 127;
      pwn[t2] = dot128(pwk + i * 128, pwk, 128, j);
    }
    gbar(cnt, NBLK * (++bar));
  }

  // K = S * R   (K[t1*256 + t0])
  {
    int t1 = tid >> 8, t0 = tid & 255;
    Kv[tid] = dot128(S + t1 * 128, R, 256, t0);
  }
}

// ---------------------------------------------------------------------------
// Conv partials: task (m,c), c<=m, output tile m (1024 outputs), s-chunk c
// (1024 K values). 528 blocks. XOR-swizzled LDS for conflict-free float4
// u-reads; register window shift: one new float4 per 4 s-steps.
// ---------------------------------------------------------------------------
__global__ __launch_bounds__(256) void conv_k(const float* __restrict__ u,
                                              const float* __restrict__ Kv,
                                              float* __restrict__ Pp) {
  __shared__ __align__(16) float ks[1024];
  __shared__ __align__(16) float usw[2048];

  int bid = blockIdx.x, tid = threadIdx.x;
  int m = 0;
  while ((m + 1) * (m + 2) / 2 <= bid) m++;
  int c = bid - m * (m + 1) / 2;
  int w0 = (m - c - 1) << 10;  // logical us[li] = u[w0 + li]

  for (int idx = tid; idx < 1024; idx += 256) ks[idx] = Kv[(c << 10) + idx];
  for (int idx = tid; idx < 2048; idx += 256) {
    int gi = w0 + idx;
    float v = (gi >= 0) ? u[gi] : 0.f;
    int b = idx >> 2;
    int pb = b ^ ((b >> 3) & 7);
    usw[(pb << 2) | (idx & 3)] = v;
  }
  __syncthreads();

  int tb = tid << 2;

#define LD4(x)                                                      \
  (*(const float4*)&usw[((((x) >> 2) ^ ((((x) >> 2) >> 3) & 7)) << 2)])

  float4 wlo = LD4(1020 + tb);   // logical us[1020+tb .. 1023+tb]
  float4 whi = LD4(1024 + tb);   // logical us[1024+tb .. 1027+tb]
  float acc0 = 0.f, acc1 = 0.f, acc2 = 0.f, acc3 = 0.f;

#pragma unroll 4
  for (int s8 = 0; s8 < 1024; s8 += 4) {
    float4 k4 = *(const float4*)&ks[s8];
    // acc[i] += k4[ds] * w[4 + i - ds],  w[0..3]=wlo, w[4..7]=whi
    acc0 = fmaf(k4.x, whi.x, acc0);
    acc0 = fmaf(k4.y, wlo.w, acc0);
    acc0 = fmaf(k4.z, wlo.z, acc0);
    acc0 = fmaf(k4.w, wlo.y, acc0);
    acc1 = fmaf(k4.x, whi.y, acc1);
    acc1 = fmaf(k4.y, whi.x, acc1);
    acc1 = fmaf(k4.z, wlo.w, acc1);
    acc1 = fmaf(k4.w, wlo.z, acc1);
    acc2 = fmaf(k4.x, whi.z, acc2);
    acc2 = fmaf(k4.y, whi.y, acc2);
    acc2 = fmaf(k4.z, whi.x, acc2);
    acc2 = fmaf(k4.w, wlo.w, acc2);
    acc3 = fmaf(k4.x, whi.w, acc3);
    acc3 = fmaf(k4.y, whi.z, acc3);
    acc3 = fmaf(k4.z, whi.y, acc3);
    acc3 = fmaf(k4.w, whi.x, acc3);
    if (s8 < 1020) {             // shift window down by 4, load next float4
      whi = wlo;
      wlo = LD4(1016 + tb - s8);
    }
  }
#undef LD4

  float* dst = Pp + (c << 15) + (m << 10) + tb;
  *(float4*)dst = make_float4(acc0, acc1, acc2, acc3);
}

// ---------------------------------------------------------------------------
// reduce: y[t] = D*u[t] + sum_{c<=t>>10} P[c][t]
// ---------------------------------------------------------------------------
__global__ __launch_bounds__(256) void reduce_k(const float* __restrict__ Pp,
                                                const float* __restrict__ u,
                                                const float* __restrict__ D,
                                                float* __restrict__ y) {
  int t = blockIdx.x * 256 + threadIdx.x;
  if (t >= L_SEQ) return;
  int mm = t >> 10;
  float acc = D[0] * u[t];
  for (int c = 0; c <= mm; ++c) acc += Pp[(c << 15) + t];
  y[t] = acc;
}

// ---------------------------------------------------------------------------
// host side
// ---------------------------------------------------------------------------
extern "C" void kernel_launch(void* const* d_in, const int* in_sizes, int n_in,
                              void* d_out, int out_size, void* d_ws, size_t ws_size,
                              hipStream_t stream) {
  (void)in_sizes; (void)n_in; (void)out_size; (void)ws_size;
  const float* u     = (const float*)d_in[0];
  const float* A     = (const float*)d_in[1];
  const float* B     = (const float*)d_in[2];
  const float* C     = (const float*)d_in[3];
  const float* D     = (const float*)d_in[4];
  const float* lstep = (const float*)d_in[5];
  float* y  = (float*)d_out;
  float* ws = (float*)d_ws;

  // layout (floats): [0..16) cnt+pad | 10 matrices of 16384 | R 32768 |
  //                  S 16384 | Kv 32768 | Pp 32*32768
  float* Kv = ws + 16 + 10 * 16384 + 32768 + 16384;  // 213008
  float* Pp = Kv + 32768;                            // 245776

  hipMemsetAsync(d_ws, 0, 64, stream);  // zero the barrier counter
  hipLaunchKernelGGL(chain_k, dim3(NBLK), dim3(256), 0, stream, A, B, C, lstep, ws);
  hipLaunchKernelGGL(conv_k, dim3(528), dim3(256), 0, stream, u, Kv, Pp);
  hipLaunchKernelGGL(reduce_k, dim3(L_SEQ / 256), dim3(256), 0, stream, Pp, u, D, y);
}

// Round 3
// 218.512 us; speedup vs baseline: 1.2710x; 1.2710x over previous
//
#include <hip/hip_runtime.h>
#include <math.h>

#define L_SEQ 32768
#define LDB 136   // bf16 elements per LDS row (272 B = 17 x 16 B -> conflict-free b128)

typedef float f32x4 __attribute__((ext_vector_type(4)));
typedef short bf16x8 __attribute__((ext_vector_type(8)));

__device__ __forceinline__ unsigned short f2bf(float x) {
  unsigned u = __float_as_uint(x);
  u = u + 0x7FFFu + ((u >> 16) & 1u);
  return (unsigned short)(u >> 16);
}
__device__ __forceinline__ float bf2f(unsigned short h) {
  return __uint_as_float(((unsigned)h) << 16);
}

// ---------------------------------------------------------------------------
// One 128xN = 128x128 * 128xN multiply on a single 1024-thread block.
// Operands staged to LDS as bf16 hi/lo (A row-major, B transposed); fp32
// emulated via 3 bf16 MFMAs. N, M may be < 128 (powers of two); Nc = 1<<lgNc
// is the staged column count (>=32, cols >= N zero-filled).
// mode: 0 out=acc ; 1 +=E1 ; 2 +=E1+E2+I ; 3 out=c3*acc-I
// ---------------------------------------------------------------------------
__device__ __forceinline__ void mm_step(
    unsigned short* lds, float* gOut, int ldc, int M, int N,
    const float* gA, int stageA, const float* gB, int ldb, int stageB,
    int lgNc, int mode, const float* E1, const float* E2, float c3) {
  unsigned short* OPAh = lds;
  unsigned short* OPAl = lds + 128 * LDB;
  unsigned short* OPBh = lds + 2 * 128 * LDB;
  unsigned short* OPBl = lds + 3 * 128 * LDB;
  int t = threadIdx.x;
  int Nc = 1 << lgNc;
  __syncthreads();   // protect LDS from prior step's readers
  if (stageA) {
    int Mc8 = ((M + 15) & ~15) << 3;
    if (t < Mc8) {
      int row = t >> 3, c0 = (t & 7) << 4;
      const float* src = gA + row * 128 + c0;
      bf16x8 h0, h1, l0, l1;
#pragma unroll
      for (int i = 0; i < 8; ++i) {
        float x = src[i];
        unsigned short h = f2bf(x);
        h0[i] = (short)h;
        l0[i] = (short)f2bf(x - bf2f(h));
      }
#pragma unroll
      for (int i = 0; i < 8; ++i) {
        float x = src[8 + i];
        unsigned short h = f2bf(x);
        h1[i] = (short)h;
        l1[i] = (short)f2bf(x - bf2f(h));
      }
      int off = row * LDB + c0;
      *(bf16x8*)&OPAh[off] = h0;
      *(bf16x8*)&OPAh[off + 8] = h1;
      *(bf16x8*)&OPAl[off] = l0;
      *(bf16x8*)&OPAl[off + 8] = l1;
    }
  }
  if (stageB) {
    if (t < (Nc << 3)) {
      int col = t & (Nc - 1);
      int k0 = (t >> lgNc) << 4;
      bf16x8 h0, h1, l0, l1;
#pragma unroll
      for (int i = 0; i < 8; ++i) {
        float x = (col < N) ? gB[(k0 + i) * ldb + col] : 0.f;
        unsigned short h = f2bf(x);
        h0[i] = (short)h;
        l0[i] = (short)f2bf(x - bf2f(h));
      }
#pragma unroll
      for (int i = 0; i < 8; ++i) {
        float x = (col < N) ? gB[(k0 + 8 + i) * ldb + col] : 0.f;
        unsigned short h = f2bf(x);
        h1[i] = (short)h;
        l1[i] = (short)f2bf(x - bf2f(h));
      }
      int off = col * LDB + k0;
      *(bf16x8*)&OPBh[off] = h0;
      *(bf16x8*)&OPBh[off + 8] = h1;
      *(bf16x8*)&OPBl[off] = l0;
      *(bf16x8*)&OPBl[off + 8] = l1;
    }
  }
  __syncthreads();

  int w = t >> 6, lane = t & 63;
  int r0 = (w >> 2) << 5, c0 = (w & 3) << 5;
  if (r0 < M && c0 < N) {
    f32x4 a00 = {0.f, 0.f, 0.f, 0.f}, a01 = a00, a10 = a00, a11 = a00;
    int la = lane & 15, lg = lane >> 4;
#pragma unroll
    for (int kb = 0; kb < 4; ++kb) {
      int kpos = (kb << 5) + (lg << 3);
      bf16x8 ah0 = *(const bf16x8*)&OPAh[(r0 + la) * LDB + kpos];
      bf16x8 al0 = *(const bf16x8*)&OPAl[(r0 + la) * LDB + kpos];
      bf16x8 ah1 = *(const bf16x8*)&OPAh[(r0 + 16 + la) * LDB + kpos];
      bf16x8 al1 = *(const bf16x8*)&OPAl[(r0 + 16 + la) * LDB + kpos];
      bf16x8 bh0 = *(const bf16x8*)&OPBh[(c0 + la) * LDB + kpos];
      bf16x8 bl0 = *(const bf16x8*)&OPBl[(c0 + la) * LDB + kpos];
      bf16x8 bh1 = *(const bf16x8*)&OPBh[(c0 + 16 + la) * LDB + kpos];
      bf16x8 bl1 = *(const bf16x8*)&OPBl[(c0 + 16 + la) * LDB + kpos];
      a00 = __builtin_amdgcn_mfma_f32_16x16x32_bf16(ah0, bh0, a00, 0, 0, 0);
      a00 = __builtin_amdgcn_mfma_f32_16x16x32_bf16(ah0, bl0, a00, 0, 0, 0);
      a00 = __builtin_amdgcn_mfma_f32_16x16x32_bf16(al0, bh0, a00, 0, 0, 0);
      a01 = __builtin_amdgcn_mfma_f32_16x16x32_bf16(ah0, bh1, a01, 0, 0, 0);
      a01 = __builtin_amdgcn_mfma_f32_16x16x32_bf16(ah0, bl1, a01, 0, 0, 0);
      a01 = __builtin_amdgcn_mfma_f32_16x16x32_bf16(al0, bh1, a01, 0, 0, 0);
      a10 = __builtin_amdgcn_mfma_f32_16x16x32_bf16(ah1, bh0, a10, 0, 0, 0);
      a10 = __builtin_amdgcn_mfma_f32_16x16x32_bf16(ah1, bl0, a10, 0, 0, 0);
      a10 = __builtin_amdgcn_mfma_f32_16x16x32_bf16(al1, bh0, a10, 0, 0, 0);
      a11 = __builtin_amdgcn_mfma_f32_16x16x32_bf16(ah1, bh1, a11, 0, 0, 0);
      a11 = __builtin_amdgcn_mfma_f32_16x16x32_bf16(ah1, bl1, a11, 0, 0, 0);
      a11 = __builtin_amdgcn_mfma_f32_16x16x32_bf16(al1, bh1, a11, 0, 0, 0);
    }
#pragma unroll
    for (int ri = 0; ri < 2; ++ri)
#pragma unroll
      for (int ci = 0; ci < 2; ++ci) {
        f32x4 av = (ri == 0) ? ((ci == 0) ? a00 : a01) : ((ci == 0) ? a10 : a11);
#pragma unroll
        for (int r = 0; r < 4; ++r) {
          int row = r0 + (ri << 4) + (lg << 2) + r;
          int col = c0 + (ci << 4) + la;
          if (row < M && col < N) {
            float v = av[r];
            if (mode == 1) v += E1[row * 128 + col];
            else if (mode == 2) v += E1[row * 128 + col] + E2[row * 128 + col] +
                                     ((row == col) ? 1.f : 0.f);
            else if (mode == 3) v = c3 * v - ((row == col) ? 1.f : 0.f);
            gOut[row * ldc + col] = v;
          }
        }
      }
  }
  __threadfence_block();  // global writes visible to next step's staging
}

// ---------------------------------------------------------------------------
// Whole matrix chain in ONE block: Neumann inverse -> ab -> power doubling
// for R (128x256) and S (128x128) -> K = S*R.  __syncthreads-only sync.
// ---------------------------------------------------------------------------
__global__ void __launch_bounds__(1024) chain_mfma(const float* __restrict__ A,
                                                   const float* __restrict__ Bv,
                                                   const float* __restrict__ Cv,
                                                   const float* __restrict__ lstep,
                                                   float* ws) {
  extern __shared__ unsigned short lds[];
  float* T   = ws;
  float* U1  = ws + 16384;
  float* T2  = ws + 32768;
  float* T4  = ws + 49152;
  float* T8  = ws + 65536;
  float* U12 = ws + 81920;
  float* U48 = ws + 98304;
  float* P0  = ws + 114688;
  float* P1  = ws + 131072;
  float* R   = ws + 147456;   // 128 x 256 row-major
  float* S   = ws + 180224;   // 128 x 128 row-major
  float* Kv  = ws + 196608;   // 128 x 256 (flat K[t])

  int t = threadIdx.x;
  float step = expf(lstep[0]);
  float alpha = 0.5f * step / (1.0f + step);

  // s0: T = alpha*(A+2I); U1 = I + T
#pragma unroll
  for (int i = 0; i < 16; ++i) {
    int idx = t + (i << 10);
    int r = idx >> 7, c = idx & 127;
    float d = (r == c) ? 1.f : 0.f;
    float tv = alpha * (A[idx] + 2.f * d);
    T[idx] = tv;
    U1[idx] = tv + d;
  }
  __threadfence_block();

  // Neumann: inv(I-T)*(1+step)/... via (I+T)(I+T2)(I+T4)(I+T8)
  mm_step(lds, T2, 128, 128, 128, T, 1, T, 128, 1, 7, 0, 0, 0, 0.f);
  mm_step(lds, T4, 128, 128, 128, T2, 1, T2, 128, 1, 7, 0, 0, 0, 0.f);
  mm_step(lds, U12, 128, 128, 128, U1, 1, T2, 128, 0, 7, 1, U1, 0, 0.f);
  mm_step(lds, T8, 128, 128, 128, T4, 1, T4, 128, 1, 7, 0, 0, 0, 0.f);
  mm_step(lds, U48, 128, 128, 128, T4, 0, T8, 128, 1, 7, 2, T4, T8, 0.f);
  mm_step(lds, P0, 128, 128, 128, U12, 1, U48, 128, 1, 7, 3, 0, 0,
          2.f / (1.f + step));   // ab = pw(0)

  // prep: R col0 = bb = (step/2)*(ab*B + B) ; S row0 = C
  __syncthreads();
  if (t < 128) {
    float acc = 0.f;
    const float* row = P0 + t * 128;
    for (int k = 0; k < 128; ++k) acc = fmaf(row[k], Bv[k], acc);
    R[t * 256] = 0.5f * step * (acc + Bv[t]);
  } else if (t < 256) {
    S[t - 128] = Cv[t - 128];
  }
  __threadfence_block();

  // R doubling, k=0..7: pw(k+1)=pw(k)^2 ; R[:,2^k+j]=pw(k)*R[:,j]
  for (int k = 0; k < 8; ++k) {
    const float* pwk = (k & 1) ? P1 : P0;
    float* pwn = ((k + 1) & 1) ? P1 : P0;
    mm_step(lds, pwn, 128, 128, 128, pwk, 1, pwk, 128, 1, 7, 0, 0, 0, 0.f);
    mm_step(lds, R + (1 << k), 256, 128, 1 << k, pwk, 0, R, 256, 1,
            (k < 5 ? 5 : k), 0, 0, 0, 0.f);
  }
  // S doubling, k=0..6: S[2^k+i,:]=S[i,:]*pw(8+k) ; pw(9+k)=pw(8+k)^2
  for (int k = 0; k < 7; ++k) {
    const float* pwk = ((8 + k) & 1) ? P1 : P0;
    float* pwn = ((9 + k) & 1) ? P1 : P0;
    mm_step(lds, S + (1 << k) * 128, 128, 1 << k, 128, S, 1, pwk, 128, 1, 7,
            0, 0, 0, 0.f);
    if (k < 6)
      mm_step(lds, pwn, 128, 128, 128, pwk, 1, pwk, 128, 0, 7, 0, 0, 0, 0.f);
  }
  // K = S * R (two 128-col halves)
  mm_step(lds, Kv, 256, 128, 128, S, 1, R, 256, 1, 7, 0, 0, 0, 0.f);
  mm_step(lds, Kv + 128, 256, 128, 128, S, 0, R + 128, 256, 1, 7, 0, 0, 0, 0.f);
}

// ---------------------------------------------------------------------------
// Conv partials (unchanged from round 2): task (m,c), c<=m, 528 blocks,
// XOR-swizzled LDS, register window shift.
// ---------------------------------------------------------------------------
__global__ __launch_bounds__(256) void conv_k(const float* __restrict__ u,
                                              const float* __restrict__ Kv,
                                              float* __restrict__ Pp) {
  __shared__ __align__(16) float ks[1024];
  __shared__ __align__(16) float usw[2048];

  int bid = blockIdx.x, tid = threadIdx.x;
  int m = 0;
  while ((m + 1) * (m + 2) / 2 <= bid) m++;
  int c = bid - m * (m + 1) / 2;
  int w0 = (m - c - 1) << 10;

  for (int idx = tid; idx < 1024; idx += 256) ks[idx] = Kv[(c << 10) + idx];
  for (int idx = tid; idx < 2048; idx += 256) {
    int gi = w0 + idx;
    float v = (gi >= 0) ? u[gi] : 0.f;
    int b = idx >> 2;
    int pb = b ^ ((b >> 3) & 7);
    usw[(pb << 2) | (idx & 3)] = v;
  }
  __syncthreads();

  int tb = tid << 2;

#define LD4(x)                                                      \
  (*(const float4*)&usw[((((x) >> 2) ^ ((((x) >> 2) >> 3) & 7)) << 2)])

  float4 wlo = LD4(1020 + tb);
  float4 whi = LD4(1024 + tb);
  float acc0 = 0.f, acc1 = 0.f, acc2 = 0.f, acc3 = 0.f;

#pragma unroll 4
  for (int s8 = 0; s8 < 1024; s8 += 4) {
    float4 k4 = *(const float4*)&ks[s8];
    acc0 = fmaf(k4.x, whi.x, acc0);
    acc0 = fmaf(k4.y, wlo.w, acc0);
    acc0 = fmaf(k4.z, wlo.z, acc0);
    acc0 = fmaf(k4.w, wlo.y, acc0);
    acc1 = fmaf(k4.x, whi.y, acc1);
    acc1 = fmaf(k4.y, whi.x, acc1);
    acc1 = fmaf(k4.z, wlo.w, acc1);
    acc1 = fmaf(k4.w, wlo.z, acc1);
    acc2 = fmaf(k4.x, whi.z, acc2);
    acc2 = fmaf(k4.y, whi.y, acc2);
    acc2 = fmaf(k4.z, whi.x, acc2);
    acc2 = fmaf(k4.w, wlo.w, acc2);
    acc3 = fmaf(k4.x, whi.w, acc3);
    acc3 = fmaf(k4.y, whi.z, acc3);
    acc3 = fmaf(k4.z, whi.y, acc3);
    acc3 = fmaf(k4.w, whi.x, acc3);
    if (s8 < 1020) {
      whi = wlo;
      wlo = LD4(1016 + tb - s8);
    }
  }
#undef LD4

  float* dst = Pp + (c << 15) + (m << 10) + tb;
  *(float4*)dst = make_float4(acc0, acc1, acc2, acc3);
}

// ---------------------------------------------------------------------------
// reduce: y[t] = D*u[t] + sum_{c<=t>>10} P[c][t]
// ---------------------------------------------------------------------------
__global__ __launch_bounds__(256) void reduce_k(const float* __restrict__ Pp,
                                                const float* __restrict__ u,
                                                const float* __restrict__ D,
                                                float* __restrict__ y) {
  int t = blockIdx.x * 256 + threadIdx.x;
  if (t >= L_SEQ) return;
  int mm = t >> 10;
  float acc = D[0] * u[t];
  for (int c = 0; c <= mm; ++c) acc += Pp[(c << 15) + t];
  y[t] = acc;
}

// ---------------------------------------------------------------------------
// host side
// ---------------------------------------------------------------------------
extern "C" void kernel_launch(void* const* d_in, const int* in_sizes, int n_in,
                              void* d_out, int out_size, void* d_ws, size_t ws_size,
                              hipStream_t stream) {
  (void)in_sizes; (void)n_in; (void)out_size; (void)ws_size;
  const float* u     = (const float*)d_in[0];
  const float* A     = (const float*)d_in[1];
  const float* B     = (const float*)d_in[2];
  const float* C     = (const float*)d_in[3];
  const float* D     = (const float*)d_in[4];
  const float* lstep = (const float*)d_in[5];
  float* y  = (float*)d_out;
  float* ws = (float*)d_ws;

  float* Kv = ws + 196608;
  float* Pp = ws + 229376;   // 32 x 32768 partials

  (void)hipFuncSetAttribute((const void*)chain_mfma,
                            hipFuncAttributeMaxDynamicSharedMemorySize, 139264);
  hipLaunchKernelGGL(chain_mfma, dim3(1), dim3(1024), 139264, stream,
                     A, B, C, lstep, ws);
  hipLaunchKernelGGL(conv_k, dim3(528), dim3(256), 0, stream, u, Kv, Pp);
  hipLaunchKernelGGL(reduce_k, dim3(L_SEQ / 256), dim3(256), 0, stream, Pp, u, D, y);
}